// Round 4
// baseline (570.703 us; speedup 1.0000x reference)
//
#include <hip/hip_runtime.h>
#include <hip/hip_bf16.h>

typedef unsigned char u8;
typedef unsigned short u16;
typedef unsigned int u32;
typedef __attribute__((ext_vector_type(8))) short bf8;
typedef __attribute__((ext_vector_type(4))) float f4;

#define B_ 256
#define O_ 128
#define Hh_ 512
#define H_ 1024
#define DF_ 1536
#define I_ 2048

// ws layout (bytes)
#define HWE_OFF   0          // 256*512 f32   = 524288
#define XC_OFF    524288     // 256*4096 bf16 = 2097152
#define PRE_OFF   2621440    // 4*256*1024 f32 = 4194304
#define FLAG_OFF  6815744    // 2 ints: [0]=mask width (1/2/4), [1]=isf32

__device__ __forceinline__ float bflo(u32 u){ union{u32 i; float f;} v; v.i = u<<16; return v.f; }
__device__ __forceinline__ float bfhi(u32 u){ union{u32 i; float f;} v; v.i = u & 0xffff0000u; return v.f; }
__device__ __forceinline__ float bf1(u16 u){ union{u32 i; float f;} v; v.i = ((u32)u)<<16; return v.f; }
__device__ __forceinline__ u16 f2bf(float f){
    __hip_bfloat16 h = __float2bfloat16(f);
    union{ __hip_bfloat16 h; u16 u; } v; v.h = h; return v.u;
}
__device__ __forceinline__ u32 pack2(float a, float b){
    return ((u32)f2bf(a)) | (((u32)f2bf(b))<<16);
}
// load 8 consecutive elements (idx multiple of 8) as packed bf16
__device__ __forceinline__ uint4 load8(const void* p, size_t idx, int isf32){
    if(isf32){
        const float4* f = (const float4*)((const float*)p + idx);
        float4 x = f[0], y = f[1];
        uint4 r;
        r.x = pack2(x.x, x.y); r.y = pack2(x.z, x.w);
        r.z = pack2(y.x, y.y); r.w = pack2(y.z, y.w);
        return r;
    }
    return *(const uint4*)((const u16*)p + idx);
}
__device__ __forceinline__ float loads(const void* p, size_t idx, int isf32){
    return isf32 ? ((const float*)p)[idx] : bf1(((const u16*)p)[idx]);
}
__device__ __forceinline__ float fast_tanh(float x){
    return 1.0f - 2.0f/(__expf(2.0f*x)+1.0f);
}
__device__ __forceinline__ float sigmoidf_(float x){
    return 1.0f/(1.0f+__expf(-x));
}

// ---------------- dtype detection ----------------
__global__ void k_detect(const u8* __restrict__ m, const u16* __restrict__ xj,
                         int* __restrict__ flags){
    __shared__ int n1, n2, n3, mb, xo;
    int t = threadIdx.x;
    if(t==0){ n1=0; n2=0; n3=0; mb=0; xo=0; }
    __syncthreads();
    int a1=0, a2=0, a3=0, amax=0;
    for(int i=t; i<B_*O_; i+=256){
        int v = m[i]; int c = i&3;
        if(c==1) a1|=v;
        if(c==2) a2|=v;
        if(c==3) a3|=v;
        amax = amax > v ? amax : v;
    }
    if(a1) atomicOr(&n1,1);
    if(a2) atomicOr(&n2,1);
    if(a3) atomicOr(&n3,1);
    atomicMax(&mb, amax);
    int e = 0;
    for(int i=t; i<4096; i+=256){
        u32 u = xj[2*i];
        int ex = (u>>7)&0xFF;
        if(ex >= 156) e = 1;
    }
    if(e) atomicOr(&xo,1);
    __syncthreads();
    if(t==0){
        int w;
        if(!n1 && !n2 && !n3)      w = 4;   // int32
        else if(!n1 && n2 && n3)   w = 4;   // f32
        else if(mb > 1)            w = 2;   // bf16
        else                       w = 1;   // bool8
        flags[0] = w;
        flags[1] = xo;
    }
}

// ---------------- hwe GEMM: hwe[b,n] = h[b,:] . We[n,:], M=256,N=64/block,K=1024 ----------------
__global__ __launch_bounds__(512) void k_hwe(const void* __restrict__ h,
                                             const void* __restrict__ We,
                                             const int* __restrict__ flags,
                                             float* __restrict__ hwe){
    int n0 = blockIdx.x*64;
    int t = threadIdx.x;
    int isf32 = flags[1];
    __shared__ __align__(16) u16 As[256*40];
    __shared__ __align__(16) u16 Bs[64*40];
    int w = t>>6, lane = t&63;
    int q = lane>>4, l16 = lane&15;
    int koff = q*8;
    f4 acc[2][4];
    for(int mi=0;mi<2;mi++) for(int ni=0;ni<4;ni++){
        f4 z = {0.f,0.f,0.f,0.f}; acc[mi][ni] = z;
    }
    for(int ks=0; ks<H_; ks+=32){
        __syncthreads();
        for(int i=0;i<2;i++){
            int row = i*128 + (t>>2), cv = t&3;
            uint4 va = load8(h, (size_t)row*H_ + ks + cv*8, isf32);
            *(uint4*)&As[row*40 + cv*8] = va;
        }
        if(t < 256){
            int row = t>>2, cv = t&3;
            uint4 vb = load8(We, (size_t)(n0+row)*H_ + ks + cv*8, isf32);
            *(uint4*)&Bs[row*40 + cv*8] = vb;
        }
        __syncthreads();
        bf8 af[2], bfr[4];
        for(int mi=0;mi<2;mi++) af[mi]  = *(const bf8*)&As[(w*32+mi*16+l16)*40 + koff];
        for(int ni=0;ni<4;ni++) bfr[ni] = *(const bf8*)&Bs[(ni*16+l16)*40 + koff];
        for(int mi=0;mi<2;mi++)
            for(int ni=0;ni<4;ni++)
                acc[mi][ni] = __builtin_amdgcn_mfma_f32_16x16x32_bf16(af[mi], bfr[ni], acc[mi][ni], 0,0,0);
    }
    for(int mi=0;mi<2;mi++){
        for(int r=0;r<4;r++){
            int brow = w*32 + mi*16 + q*4 + r;
            for(int ni=0;ni<4;ni++){
                int ncol = n0 + ni*16 + l16;
                hwe[(size_t)brow*Hh_ + ncol] = acc[mi][ni][r];
            }
        }
    }
}

// ---------------- pack X_F | h | c into Xc[512:4096) as bf16 ----------------
__global__ __launch_bounds__(256) void k_pack(const void* __restrict__ XF,
                                              const void* __restrict__ h,
                                              const void* __restrict__ c,
                                              const int* __restrict__ flags,
                                              u16* __restrict__ Xc){
    int b = blockIdx.y;
    int r = blockIdx.x*256 + threadIdx.x;   // 0..3583
    int isf32 = flags[1];
    float v;
    if(r < DF_)            v = loads(XF, (size_t)b*DF_ + r, isf32);
    else if(r < DF_ + H_)  v = loads(h,  (size_t)b*H_ + (r - DF_), isf32);
    else                   v = loads(c,  (size_t)b*H_ + (r - DF_ - H_), isf32);
    Xc[(size_t)b*4096 + 512 + r] = f2bf(v);
}

// ---------------- fused attention ----------------
__global__ __launch_bounds__(256) void k_attn(const void* __restrict__ xj,
                                              const void* __restrict__ maskp,
                                              const void* __restrict__ wvec,
                                              const void* __restrict__ Ue,
                                              const void* __restrict__ be,
                                              const float* __restrict__ hwe,
                                              const int* __restrict__ flags,
                                              u16* __restrict__ Xc){
    int b = blockIdx.x, t = threadIdx.x;
    int isf32 = flags[1];
    int mw = flags[0];
    __shared__ __align__(16) u16 As[128*40];
    __shared__ __align__(16) u16 Bs[128*40];
    __shared__ float hwes[Hh_];
    __shared__ float wvs[Hh_];
    __shared__ float es[O_];
    __shared__ float as_[O_];
    __shared__ float red[2];

    for(int i=0;i<2;i++){
        int k = t + i*256;
        hwes[k] = hwe[(size_t)b*Hh_ + k] + loads(be, k, isf32);
        wvs[k]  = loads(wvec, k, isf32);
    }
    if(t < O_) es[t] = 0.f;

    const size_t xboff = (size_t)b*O_*Hh_;

    int w = t>>6, lane = t&63;
    int wm = w>>1, wn = w&1;
    int q = lane>>4, l16 = lane&15;
    int koff = q*8;

    for(int nc=0; nc<4; nc++){
        f4 acc[4][4];
        for(int mi=0;mi<4;mi++) for(int ni=0;ni<4;ni++){
            f4 z = {0.f,0.f,0.f,0.f}; acc[mi][ni] = z;
        }
        for(int ks=0; ks<Hh_; ks+=32){
            __syncthreads();
            for(int i=0;i<2;i++){
                int qq = t + i*256;
                int row = qq>>2, cv = qq&3;
                uint4 va = load8(xj, xboff + (size_t)row*Hh_ + ks + cv*8, isf32);
                *(uint4*)&As[row*40 + cv*8] = va;
                uint4 vb = load8(Ue, (size_t)(nc*128 + row)*Hh_ + ks + cv*8, isf32);
                *(uint4*)&Bs[row*40 + cv*8] = vb;
            }
            __syncthreads();
            bf8 af[4], bfr[4];
            for(int mi=0;mi<4;mi++) af[mi]  = *(const bf8*)&As[(wm*64+mi*16+l16)*40 + koff];
            for(int ni=0;ni<4;ni++) bfr[ni] = *(const bf8*)&Bs[(wn*64+ni*16+l16)*40 + koff];
            for(int mi=0;mi<4;mi++)
                for(int ni=0;ni<4;ni++)
                    acc[mi][ni] = __builtin_amdgcn_mfma_f32_16x16x32_bf16(af[mi], bfr[ni], acc[mi][ni], 0,0,0);
        }
        for(int mi=0;mi<4;mi++){
            for(int r=0;r<4;r++){
                int o = wm*64 + mi*16 + q*4 + r;
                float part = 0.f;
                for(int ni=0;ni<4;ni++){
                    int col = nc*128 + wn*64 + ni*16 + l16;
                    part += wvs[col] * fast_tanh(hwes[col] + acc[mi][ni][r]);
                }
                part += __shfl_xor(part, 1);
                part += __shfl_xor(part, 2);
                part += __shfl_xor(part, 4);
                part += __shfl_xor(part, 8);
                if(l16 == 0) atomicAdd(&es[o], part);
            }
        }
    }
    __syncthreads();
    if(t < O_){
        size_t mi_ = (size_t)b*O_ + t;
        bool valid;
        if(mw == 1)      valid = ((const u8*)maskp)[mi_]  != 0;
        else if(mw == 2) valid = ((const u16*)maskp)[mi_] != 0;
        else             valid = ((const u32*)maskp)[mi_] != 0;
        es[t] = valid ? es[t] : -1e30f;
    }
    __syncthreads();
    if(t < 64){
        float v = fmaxf(es[t], es[t+64]);
        for(int m=32;m>0;m>>=1) v = fmaxf(v, __shfl_xor(v, m));
        if(t==0) red[0] = v;
    }
    __syncthreads();
    float mx = red[0];
    if(t < O_) as_[t] = __expf(es[t] - mx);
    __syncthreads();
    if(t < 64){
        float v = as_[t] + as_[t+64];
        for(int m=32;m>0;m>>=1) v += __shfl_xor(v, m);
        if(t==0) red[1] = v;
    }
    __syncthreads();
    float inv = 1.0f / red[1];
    {
        float a0 = 0.f, a1 = 0.f;
        for(int o=0;o<O_;o++){
            float av = as_[o] * inv;
            a0 += av * loads(xj, xboff + (size_t)o*Hh_ + 2*t,     isf32);
            a1 += av * loads(xj, xboff + (size_t)o*Hh_ + 2*t + 1, isf32);
        }
        u16* xcrow = Xc + (size_t)b*4096;
        xcrow[2*t]   = f2bf(a0);
        xcrow[2*t+1] = f2bf(a1);
    }
}

// ---------------- gates GEMM: M=256 (all b), N=64/block, grid 64 ----------------
__global__ __launch_bounds__(512) void k_gates(const u16* __restrict__ Xc,
    const void* __restrict__ Wi, const void* __restrict__ Wf, const void* __restrict__ Wc, const void* __restrict__ Wo,
    const void* __restrict__ Ui, const void* __restrict__ Uf, const void* __restrict__ Uc, const void* __restrict__ Uo,
    const void* __restrict__ Vi, const void* __restrict__ Vf, const void* __restrict__ Vo,
    const int* __restrict__ flags,
    float* __restrict__ pre){
    int nt = blockIdx.x;          // gate g = nt>>4, n-tile nt&15
    int g  = nt>>4;
    int isf32 = flags[1];
    const void* Wm = (g==0)?Wi:(g==1)?Wf:(g==2)?Wc:Wo;
    const void* Um = (g==0)?Ui:(g==1)?Uf:(g==2)?Uc:Uo;
    const void* Vm = (g==0)?Vi:(g==1)?Vf:(g==3)?Vo:Vi;  // g==2 never dereferences V
    int Kg = (g==2) ? 3072 : 4096;
    int n0 = (nt&15)*64;
    int t = threadIdx.x;
    __shared__ __align__(16) u16 As[256*40];
    __shared__ __align__(16) u16 Bs[64*40];
    int w = t>>6, lane = t&63;
    int q = lane>>4, l16 = lane&15;
    int koff = q*8;
    f4 acc[2][4];
    for(int mi=0;mi<2;mi++) for(int ni=0;ni<4;ni++){
        f4 z = {0.f,0.f,0.f,0.f}; acc[mi][ni] = z;
    }
    for(int ks=0; ks<Kg; ks+=32){
        __syncthreads();
        for(int i=0;i<2;i++){
            int row = i*128 + (t>>2), cv = t&3;
            uint4 va = *(const uint4*)(Xc + (size_t)row*4096 + ks + cv*8);
            *(uint4*)&As[row*40 + cv*8] = va;
        }
        if(t < 256){
            int row = t>>2, cv = t&3;
            int n = n0 + row;
            int k = ks + cv*8;
            uint4 vb;
            if(k < 2048)       vb = load8(Wm, (size_t)n*I_ + k, isf32);
            else if(k < 3072)  vb = load8(Um, (size_t)n*H_ + (k-2048), isf32);
            else               vb = load8(Vm, (size_t)n*H_ + (k-3072), isf32);
            *(uint4*)&Bs[row*40 + cv*8] = vb;
        }
        __syncthreads();
        bf8 af[2], bfr[4];
        for(int mi=0;mi<2;mi++) af[mi]  = *(const bf8*)&As[(w*32+mi*16+l16)*40 + koff];
        for(int ni=0;ni<4;ni++) bfr[ni] = *(const bf8*)&Bs[(ni*16+l16)*40 + koff];
        for(int mi=0;mi<2;mi++)
            for(int ni=0;ni<4;ni++)
                acc[mi][ni] = __builtin_amdgcn_mfma_f32_16x16x32_bf16(af[mi], bfr[ni], acc[mi][ni], 0,0,0);
    }
    float* pg = pre + (size_t)g*(B_*H_);
    for(int mi=0;mi<2;mi++){
        for(int r=0;r<4;r++){
            int brow = w*32 + mi*16 + q*4 + r;
            for(int ni=0;ni<4;ni++){
                int ncol = n0 + ni*16 + l16;
                pg[(size_t)brow*H_ + ncol] = acc[mi][ni][r];
            }
        }
    }
}

// ---------------- combine: f32 outputs ----------------
__global__ __launch_bounds__(256) void k_combine(const float* __restrict__ pre,
    const void* __restrict__ c,
    const void* __restrict__ bi, const void* __restrict__ bfv,
    const void* __restrict__ bc, const void* __restrict__ bo,
    const int* __restrict__ flags,
    float* __restrict__ out){
    int b = blockIdx.x, t = threadIdx.x;
    int isf32 = flags[1];
    const size_t G = (size_t)B_*H_;
    for(int i=0;i<4;i++){
        int n = i*256 + t;
        size_t idx = (size_t)b*H_ + n;
        float pi = pre[idx]       + loads(bi,  n, isf32);
        float pf = pre[G   + idx] + loads(bfv, n, isf32);
        float pc = pre[2*G + idx] + loads(bc,  n, isf32);
        float po = pre[3*G + idx] + loads(bo,  n, isf32);
        float ig = sigmoidf_(pi);
        float fg = sigmoidf_(pf);
        float og = sigmoidf_(po);
        float cold = loads(c, idx, isf32);
        float ncv = fg*cold + ig*fast_tanh(pc);
        float nh  = og*fast_tanh(ncv);
        out[idx]     = nh;    // new_h
        out[G + idx] = ncv;   // new_c
    }
}

extern "C" void kernel_launch(void* const* d_in, const int* in_sizes, int n_in,
                              void* d_out, int out_size, void* d_ws, size_t ws_size,
                              hipStream_t stream){
    const void* xj   = d_in[0];
    const void* mask = d_in[1];
    const void* XF   = d_in[2];
    const void* h    = d_in[3];
    const void* c    = d_in[4];
    const void* Wi   = d_in[5];
    const void* Wf   = d_in[6];
    const void* Wc   = d_in[7];
    const void* Wo   = d_in[8];
    const void* Ui   = d_in[9];
    const void* Uf   = d_in[10];
    const void* Uc   = d_in[11];
    const void* Uo   = d_in[12];
    const void* Vi   = d_in[13];
    const void* Vf   = d_in[14];
    // d_in[15] = V_c : unused by the reference
    const void* Vo   = d_in[16];
    const void* bi   = d_in[17];
    const void* bfv  = d_in[18];
    const void* bc   = d_in[19];
    const void* bo   = d_in[20];
    const void* wv   = d_in[21];
    const void* We   = d_in[22];
    const void* Ue   = d_in[23];
    const void* be   = d_in[24];

    char* ws = (char*)d_ws;
    float* hwe = (float*)(ws + HWE_OFF);
    u16*   Xc  = (u16*)(ws + XC_OFF);
    float* pre = (float*)(ws + PRE_OFF);
    int*   flags = (int*)(ws + FLAG_OFF);
    float* out = (float*)d_out;

    k_detect<<<1, 256, 0, stream>>>((const u8*)mask, (const u16*)xj, flags);
    k_hwe<<<8, 512, 0, stream>>>(h, We, flags, hwe);
    k_pack<<<dim3(14, B_), 256, 0, stream>>>(XF, h, c, flags, Xc);
    k_attn<<<B_, 256, 0, stream>>>(xj, mask, wv, Ue, be, hwe, flags, Xc);
    k_gates<<<64, 512, 0, stream>>>(Xc, Wi,Wf,Wc,Wo, Ui,Uf,Uc,Uo, Vi,Vf,Vo, flags, pre);
    k_combine<<<B_, 256, 0, stream>>>(pre, c, bi, bfv, bc, bo, flags, out);
}

// Round 5
// 346.293 us; speedup vs baseline: 1.6480x; 1.6480x over previous
//
#include <hip/hip_runtime.h>
#include <hip/hip_bf16.h>

typedef unsigned char u8;
typedef unsigned short u16;
typedef unsigned int u32;
typedef __attribute__((ext_vector_type(8))) short bf8;
typedef __attribute__((ext_vector_type(4))) float f4;

#define B_ 256
#define O_ 128
#define Hh_ 512
#define H_ 1024
#define DF_ 1536
#define I_ 2048

// ws layout (bytes) — identical footprint to R4 (proven in-bounds)
#define HWE_OFF   0          // 256*512 f32 = 524288 (memset 0, atomicAdd target)
#define XC_OFF    524288     // 256*4096 bf16 = 2097152
#define PRE_OFF   2621440    // 4*256*1024 f32 = 4194304 (memset 0 before k_gates)
                             // Epart aliases PRE: 4*32768 f32 = 524288 (disjoint lifetime)
#define FLAG_OFF  6815744    // 2 ints

__device__ __forceinline__ float bflo(u32 u){ union{u32 i; float f;} v; v.i = u<<16; return v.f; }
__device__ __forceinline__ float bfhi(u32 u){ union{u32 i; float f;} v; v.i = u & 0xffff0000u; return v.f; }
__device__ __forceinline__ float bf1(u16 u){ union{u32 i; float f;} v; v.i = ((u32)u)<<16; return v.f; }
__device__ __forceinline__ u16 f2bf(float f){
    __hip_bfloat16 h = __float2bfloat16(f);
    union{ __hip_bfloat16 h; u16 u; } v; v.h = h; return v.u;
}
__device__ __forceinline__ u32 pack2(float a, float b){
    return ((u32)f2bf(a)) | (((u32)f2bf(b))<<16);
}
__device__ __forceinline__ uint4 load8(const void* p, size_t idx, int isf32){
    if(isf32){
        const float4* f = (const float4*)((const float*)p + idx);
        float4 x = f[0], y = f[1];
        uint4 r;
        r.x = pack2(x.x, x.y); r.y = pack2(x.z, x.w);
        r.z = pack2(y.x, y.y); r.w = pack2(y.z, y.w);
        return r;
    }
    return *(const uint4*)((const u16*)p + idx);
}
__device__ __forceinline__ float loads(const void* p, size_t idx, int isf32){
    return isf32 ? ((const float*)p)[idx] : bf1(((const u16*)p)[idx]);
}
__device__ __forceinline__ float fast_tanh(float x){
    return 1.0f - 2.0f/(__expf(2.0f*x)+1.0f);
}
__device__ __forceinline__ float sigmoidf_(float x){
    return 1.0f/(1.0f+__expf(-x));
}

// ---------------- dtype detection ----------------
__global__ void k_detect(const u8* __restrict__ m, const u16* __restrict__ xj,
                         int* __restrict__ flags){
    __shared__ int n1, n2, n3, mb, xo;
    int t = threadIdx.x;
    if(t==0){ n1=0; n2=0; n3=0; mb=0; xo=0; }
    __syncthreads();
    int a1=0, a2=0, a3=0, amax=0;
    for(int i=t; i<8192; i+=256){
        int v = m[i]; int c = i&3;
        if(c==1) a1|=v;
        if(c==2) a2|=v;
        if(c==3) a3|=v;
        amax = amax > v ? amax : v;
    }
    if(a1) atomicOr(&n1,1);
    if(a2) atomicOr(&n2,1);
    if(a3) atomicOr(&n3,1);
    atomicMax(&mb, amax);
    int e = 0;
    for(int i=t; i<2048; i+=256){
        u32 u = xj[2*i];
        int ex = (u>>7)&0xFF;
        if(ex >= 156) e = 1;
    }
    if(e) atomicOr(&xo,1);
    __syncthreads();
    if(t==0){
        int w;
        if(!n1 && !n2 && !n3)      w = 4;   // int32
        else if(!n1 && n2 && n3)   w = 4;   // f32
        else if(mb > 1)            w = 2;   // bf16
        else                       w = 1;   // bool8
        flags[0] = w;
        flags[1] = xo;
    }
}

// ---------------- hwe GEMM, K-split: hwe[b,n] += h[b,kchunk] . We[n,kchunk] ----------------
// grid (8 n-tiles, 4 k-chunks, 2 m-tiles), 256 thr. Tile 128x64, K-chunk 256.
__global__ __launch_bounds__(256) void k_hwe(const void* __restrict__ h,
                                             const void* __restrict__ We,
                                             const int* __restrict__ flags,
                                             float* __restrict__ hwe){
    int n0 = blockIdx.x*64;
    int kc = blockIdx.y*256;
    int m0 = blockIdx.z*128;
    int t = threadIdx.x;
    int isf32 = flags[1];
    __shared__ __align__(16) u16 As[128*40];
    __shared__ __align__(16) u16 Bs[64*40];
    int w = t>>6, lane = t&63;
    int q = lane>>4, l16 = lane&15;
    int koff = q*8;
    f4 acc[2][4];
    for(int mi=0;mi<2;mi++) for(int ni=0;ni<4;ni++){
        f4 z = {0.f,0.f,0.f,0.f}; acc[mi][ni] = z;
    }
    for(int ks=0; ks<256; ks+=32){
        __syncthreads();
        for(int i=0;i<2;i++){
            int row = i*64 + (t>>2), cv = t&3;
            uint4 va = load8(h, (size_t)(m0+row)*H_ + kc + ks + cv*8, isf32);
            *(uint4*)&As[row*40 + cv*8] = va;
        }
        {
            int row = t>>2, cv = t&3;
            uint4 vb = load8(We, (size_t)(n0+row)*H_ + kc + ks + cv*8, isf32);
            *(uint4*)&Bs[row*40 + cv*8] = vb;
        }
        __syncthreads();
        bf8 af[2], bfr[4];
        for(int mi=0;mi<2;mi++) af[mi]  = *(const bf8*)&As[(w*32+mi*16+l16)*40 + koff];
        for(int ni=0;ni<4;ni++) bfr[ni] = *(const bf8*)&Bs[(ni*16+l16)*40 + koff];
        for(int mi=0;mi<2;mi++)
            for(int ni=0;ni<4;ni++)
                acc[mi][ni] = __builtin_amdgcn_mfma_f32_16x16x32_bf16(af[mi], bfr[ni], acc[mi][ni], 0,0,0);
    }
    for(int mi=0;mi<2;mi++){
        for(int r=0;r<4;r++){
            int brow = m0 + w*32 + mi*16 + q*4 + r;
            for(int ni=0;ni<4;ni++){
                int ncol = n0 + ni*16 + l16;
                atomicAdd(&hwe[(size_t)brow*Hh_ + ncol], acc[mi][ni][r]);
            }
        }
    }
}

// ---------------- pack X_F | h | c into Xc[512:4096) as bf16 ----------------
__global__ __launch_bounds__(256) void k_pack(const void* __restrict__ XF,
                                              const void* __restrict__ h,
                                              const void* __restrict__ c,
                                              const int* __restrict__ flags,
                                              u16* __restrict__ Xc){
    int b = blockIdx.y;
    int r = blockIdx.x*256 + threadIdx.x;   // 0..3583
    int isf32 = flags[1];
    float v;
    if(r < DF_)            v = loads(XF, (size_t)b*DF_ + r, isf32);
    else if(r < DF_ + H_)  v = loads(h,  (size_t)b*H_ + (r - DF_), isf32);
    else                   v = loads(c,  (size_t)b*H_ + (r - DF_ - H_), isf32);
    Xc[(size_t)b*4096 + 512 + r] = f2bf(v);
}

// ---------------- attention e-score GEMM: grid (256 b, 4 n-tiles), 256 thr ----------------
// Epart[nc][b*128+o] = sum over this n-tile's 128 cols of w[col]*tanh(hwe[b,col]+be[col]+xU[o,col])
__global__ __launch_bounds__(256) void k_attn(const void* __restrict__ xj,
                                              const void* __restrict__ wvec,
                                              const void* __restrict__ Ue,
                                              const void* __restrict__ be,
                                              const float* __restrict__ hwe,
                                              const int* __restrict__ flags,
                                              float* __restrict__ Epart){
    int b = blockIdx.x, nc = blockIdx.y, t = threadIdx.x;
    int isf32 = flags[1];
    __shared__ __align__(16) u16 As[128*40];
    __shared__ __align__(16) u16 Bs[128*40];
    __shared__ float hwes[128];
    __shared__ float wvs[128];
    __shared__ float es[O_];

    if(t < 128){
        int col = nc*128 + t;
        hwes[t] = hwe[(size_t)b*Hh_ + col] + loads(be, col, isf32);
        wvs[t]  = loads(wvec, col, isf32);
    }
    if(t < O_) es[t] = 0.f;

    const size_t xboff = (size_t)b*O_*Hh_;

    int w = t>>6, lane = t&63;
    int wm = w>>1, wn = w&1;
    int q = lane>>4, l16 = lane&15;
    int koff = q*8;

    f4 acc[4][4];
    for(int mi=0;mi<4;mi++) for(int ni=0;ni<4;ni++){
        f4 z = {0.f,0.f,0.f,0.f}; acc[mi][ni] = z;
    }
    for(int ks=0; ks<Hh_; ks+=32){
        __syncthreads();
        for(int i=0;i<2;i++){
            int qq = t + i*256;
            int row = qq>>2, cv = qq&3;
            uint4 va = load8(xj, xboff + (size_t)row*Hh_ + ks + cv*8, isf32);
            *(uint4*)&As[row*40 + cv*8] = va;
            uint4 vb = load8(Ue, (size_t)(nc*128 + row)*Hh_ + ks + cv*8, isf32);
            *(uint4*)&Bs[row*40 + cv*8] = vb;
        }
        __syncthreads();
        bf8 af[4], bfr[4];
        for(int mi=0;mi<4;mi++) af[mi]  = *(const bf8*)&As[(wm*64+mi*16+l16)*40 + koff];
        for(int ni=0;ni<4;ni++) bfr[ni] = *(const bf8*)&Bs[(wn*64+ni*16+l16)*40 + koff];
        for(int mi=0;mi<4;mi++)
            for(int ni=0;ni<4;ni++)
                acc[mi][ni] = __builtin_amdgcn_mfma_f32_16x16x32_bf16(af[mi], bfr[ni], acc[mi][ni], 0,0,0);
    }
    for(int mi=0;mi<4;mi++){
        for(int r=0;r<4;r++){
            int o = wm*64 + mi*16 + q*4 + r;
            float part = 0.f;
            for(int ni=0;ni<4;ni++){
                int col = wn*64 + ni*16 + l16;   // local col in this n-tile
                part += wvs[col] * fast_tanh(hwes[col] + acc[mi][ni][r]);
            }
            part += __shfl_xor(part, 1);
            part += __shfl_xor(part, 2);
            part += __shfl_xor(part, 4);
            part += __shfl_xor(part, 8);
            if(l16 == 0) atomicAdd(&es[o], part);
        }
    }
    __syncthreads();
    if(t < O_) Epart[(size_t)nc*32768 + (size_t)b*O_ + t] = es[t];
}

// ---------------- softmax + phi: grid 256 (per b), 512 thr ----------------
__global__ __launch_bounds__(512) void k_soft(const float* __restrict__ Epart,
                                              const void* __restrict__ maskp,
                                              const void* __restrict__ xj,
                                              const int* __restrict__ flags,
                                              u16* __restrict__ Xc){
    int b = blockIdx.x, t = threadIdx.x;
    int isf32 = flags[1];
    int mw = flags[0];
    __shared__ float es[O_];
    __shared__ float as_[O_];
    __shared__ float red[2];
    if(t < O_){
        float e = Epart[(size_t)b*O_ + t]
                + Epart[32768 + (size_t)b*O_ + t]
                + Epart[2*32768 + (size_t)b*O_ + t]
                + Epart[3*32768 + (size_t)b*O_ + t];
        size_t mi_ = (size_t)b*O_ + t;
        bool valid;
        if(mw == 1)      valid = ((const u8*)maskp)[mi_]  != 0;
        else if(mw == 2) valid = ((const u16*)maskp)[mi_] != 0;
        else             valid = ((const u32*)maskp)[mi_] != 0;
        es[t] = valid ? e : -1e30f;
    }
    __syncthreads();
    if(t < 64){
        float v = fmaxf(es[t], es[t+64]);
        for(int m=32;m>0;m>>=1) v = fmaxf(v, __shfl_xor(v, m));
        if(t==0) red[0] = v;
    }
    __syncthreads();
    if(t < O_) as_[t] = __expf(es[t] - red[0]);
    __syncthreads();
    if(t < 64){
        float v = as_[t] + as_[t+64];
        for(int m=32;m>0;m>>=1) v += __shfl_xor(v, m);
        if(t==0) red[1] = v;
    }
    __syncthreads();
    float inv = 1.0f / red[1];
    float acc = 0.f;
    size_t base = (size_t)b*O_*Hh_ + t;
    #pragma unroll 4
    for(int o=0;o<O_;o++){
        acc += as_[o] * loads(xj, base + (size_t)o*Hh_, isf32);
    }
    Xc[(size_t)b*4096 + t] = f2bf(acc * inv);
}

// ---------------- gates GEMM, K-split: grid (64 n-tiles, 4 k-chunks), 512 thr ----------------
__global__ __launch_bounds__(512) void k_gates(const u16* __restrict__ Xc,
    const void* __restrict__ Wi, const void* __restrict__ Wf, const void* __restrict__ Wc, const void* __restrict__ Wo,
    const void* __restrict__ Ui, const void* __restrict__ Uf, const void* __restrict__ Uc, const void* __restrict__ Uo,
    const void* __restrict__ Vi, const void* __restrict__ Vf, const void* __restrict__ Vo,
    const int* __restrict__ flags,
    float* __restrict__ pre){
    int nt = blockIdx.x;          // gate g = nt>>4, n-tile nt&15
    int kc = blockIdx.y;          // K-chunk of 1024
    int g  = nt>>4;
    if(g == 2 && kc == 3) return; // c-gate has no V peephole
    int isf32 = flags[1];
    const void* Wm = (g==0)?Wi:(g==1)?Wf:(g==2)?Wc:Wo;
    const void* Um = (g==0)?Ui:(g==1)?Uf:(g==2)?Uc:Uo;
    const void* Vm = (g==0)?Vi:(g==1)?Vf:(g==3)?Vo:Vi;  // g==2 never dereferences V
    int n0 = (nt&15)*64;
    int k0 = kc*1024;
    int t = threadIdx.x;
    __shared__ __align__(16) u16 As[256*40];
    __shared__ __align__(16) u16 Bs[64*40];
    int w = t>>6, lane = t&63;
    int q = lane>>4, l16 = lane&15;
    int koff = q*8;
    f4 acc[2][4];
    for(int mi=0;mi<2;mi++) for(int ni=0;ni<4;ni++){
        f4 z = {0.f,0.f,0.f,0.f}; acc[mi][ni] = z;
    }
    for(int ks=0; ks<1024; ks+=32){
        __syncthreads();
        for(int i=0;i<2;i++){
            int row = i*128 + (t>>2), cv = t&3;
            uint4 va = *(const uint4*)(Xc + (size_t)row*4096 + k0 + ks + cv*8);
            *(uint4*)&As[row*40 + cv*8] = va;
        }
        if(t < 256){
            int row = t>>2, cv = t&3;
            int n = n0 + row;
            int k = k0 + ks + cv*8;
            uint4 vb;
            if(k < 2048)       vb = load8(Wm, (size_t)n*I_ + k, isf32);
            else if(k < 3072)  vb = load8(Um, (size_t)n*H_ + (k-2048), isf32);
            else               vb = load8(Vm, (size_t)n*H_ + (k-3072), isf32);
            *(uint4*)&Bs[row*40 + cv*8] = vb;
        }
        __syncthreads();
        bf8 af[2], bfr[4];
        for(int mi=0;mi<2;mi++) af[mi]  = *(const bf8*)&As[(w*32+mi*16+l16)*40 + koff];
        for(int ni=0;ni<4;ni++) bfr[ni] = *(const bf8*)&Bs[(ni*16+l16)*40 + koff];
        for(int mi=0;mi<2;mi++)
            for(int ni=0;ni<4;ni++)
                acc[mi][ni] = __builtin_amdgcn_mfma_f32_16x16x32_bf16(af[mi], bfr[ni], acc[mi][ni], 0,0,0);
    }
    float* pg = pre + (size_t)g*(B_*H_);
    for(int mi=0;mi<2;mi++){
        for(int r=0;r<4;r++){
            int brow = w*32 + mi*16 + q*4 + r;
            for(int ni=0;ni<4;ni++){
                int ncol = n0 + ni*16 + l16;
                atomicAdd(&pg[(size_t)brow*H_ + ncol], acc[mi][ni][r]);
            }
        }
    }
}

// ---------------- combine: f32 outputs ----------------
__global__ __launch_bounds__(256) void k_combine(const float* __restrict__ pre,
    const void* __restrict__ c,
    const void* __restrict__ bi, const void* __restrict__ bfv,
    const void* __restrict__ bc, const void* __restrict__ bo,
    const int* __restrict__ flags,
    float* __restrict__ out){
    int b = blockIdx.x, t = threadIdx.x;
    int isf32 = flags[1];
    const size_t G = (size_t)B_*H_;
    for(int i=0;i<4;i++){
        int n = i*256 + t;
        size_t idx = (size_t)b*H_ + n;
        float pi = pre[idx]       + loads(bi,  n, isf32);
        float pf = pre[G   + idx] + loads(bfv, n, isf32);
        float pc = pre[2*G + idx] + loads(bc,  n, isf32);
        float po = pre[3*G + idx] + loads(bo,  n, isf32);
        float ig = sigmoidf_(pi);
        float fg = sigmoidf_(pf);
        float og = sigmoidf_(po);
        float cold = loads(c, idx, isf32);
        float ncv = fg*cold + ig*fast_tanh(pc);
        float nh  = og*fast_tanh(ncv);
        out[idx]     = nh;    // new_h
        out[G + idx] = ncv;   // new_c
    }
}

extern "C" void kernel_launch(void* const* d_in, const int* in_sizes, int n_in,
                              void* d_out, int out_size, void* d_ws, size_t ws_size,
                              hipStream_t stream){
    const void* xj   = d_in[0];
    const void* mask = d_in[1];
    const void* XF   = d_in[2];
    const void* h    = d_in[3];
    const void* c    = d_in[4];
    const void* Wi   = d_in[5];
    const void* Wf   = d_in[6];
    const void* Wc   = d_in[7];
    const void* Wo   = d_in[8];
    const void* Ui   = d_in[9];
    const void* Uf   = d_in[10];
    const void* Uc   = d_in[11];
    const void* Uo   = d_in[12];
    const void* Vi   = d_in[13];
    const void* Vf   = d_in[14];
    // d_in[15] = V_c : unused by the reference
    const void* Vo   = d_in[16];
    const void* bi   = d_in[17];
    const void* bfv  = d_in[18];
    const void* bc   = d_in[19];
    const void* bo   = d_in[20];
    const void* wv   = d_in[21];
    const void* We   = d_in[22];
    const void* Ue   = d_in[23];
    const void* be   = d_in[24];

    char* ws = (char*)d_ws;
    float* hwe  = (float*)(ws + HWE_OFF);
    u16*   Xc   = (u16*)(ws + XC_OFF);
    float* pre  = (float*)(ws + PRE_OFF);   // also Epart during attention phase
    int*   flags= (int*)(ws + FLAG_OFF);
    float* out  = (float*)d_out;

    k_detect<<<1, 256, 0, stream>>>((const u8*)mask, (const u16*)xj, flags);
    hipMemsetAsync(hwe, 0, (size_t)B_*Hh_*sizeof(float), stream);
    k_hwe<<<dim3(8,4,2), 256, 0, stream>>>(h, We, flags, hwe);
    k_pack<<<dim3(14, B_), 256, 0, stream>>>(XF, h, c, flags, Xc);
    k_attn<<<dim3(B_, 4), 256, 0, stream>>>(xj, wv, Ue, be, hwe, flags, pre);
    k_soft<<<B_, 512, 0, stream>>>(pre, mask, xj, flags, Xc);
    hipMemsetAsync(pre, 0, (size_t)4*B_*H_*sizeof(float), stream);
    k_gates<<<dim3(64, 4), 512, 0, stream>>>(Xc, Wi,Wf,Wc,Wo, Ui,Uf,Uc,Uo, Vi,Vf,Vo, flags, pre);
    k_combine<<<B_, 256, 0, stream>>>(pre, c, bi, bfv, bc, bo, flags, out);
}

// Round 6
// 338.574 us; speedup vs baseline: 1.6856x; 1.0228x over previous
//
#include <hip/hip_runtime.h>
#include <hip/hip_bf16.h>

typedef unsigned char u8;
typedef unsigned short u16;
typedef unsigned int u32;
typedef __attribute__((ext_vector_type(8))) short bf8;
typedef __attribute__((ext_vector_type(4))) float f4;

#define B_ 256
#define O_ 128
#define Hh_ 512
#define H_ 1024
#define DF_ 1536
#define I_ 2048

// ws layout (bytes)
#define HWE_OFF   0          // 256*512 f32 = 524288
#define XC_OFF    524288     // 256*4096 bf16 = 2097152
#define PRE_OFF   2621440    // 4*256*1024 f32 = 4194304 (Epart aliases: 8*32768 f32 = 1 MB)
#define FLAG_OFF  6815744    // ints
#define XJ16_OFF  7340032    // 16777216 bf16 = 33554432   [big-ws only]
#define UE16_OFF  40894464   // 262144 bf16 = 524288       [big-ws only]
#define WS_BIG    41418752

__device__ __forceinline__ float bflo(u32 u){ union{u32 i; float f;} v; v.i = u<<16; return v.f; }
__device__ __forceinline__ float bfhi(u32 u){ union{u32 i; float f;} v; v.i = u & 0xffff0000u; return v.f; }
__device__ __forceinline__ float bf1(u16 u){ union{u32 i; float f;} v; v.i = ((u32)u)<<16; return v.f; }
__device__ __forceinline__ u16 f2bf(float f){
    __hip_bfloat16 h = __float2bfloat16(f);
    union{ __hip_bfloat16 h; u16 u; } v; v.h = h; return v.u;
}
__device__ __forceinline__ u32 pack2(float a, float b){
    return ((u32)f2bf(a)) | (((u32)f2bf(b))<<16);
}
struct P8 { uint4 lo, hi; };
// raw fetch of 8 elements (no conversion — keeps loads off the critical path)
__device__ __forceinline__ P8 fetch8(const void* p, size_t idx, int isf32){
    P8 r;
    if(isf32){
        const uint4* f = (const uint4*)((const float*)p + idx);
        r.lo = f[0]; r.hi = f[1];
    } else {
        r.lo = *(const uint4*)((const u16*)p + idx);
    }
    return r;
}
// convert raw fetch to 8 packed bf16
__device__ __forceinline__ uint4 cvt8(P8 r, int isf32){
    if(isf32){
        float4 x = *(float4*)&r.lo, y = *(float4*)&r.hi;
        uint4 o;
        o.x = pack2(x.x,x.y); o.y = pack2(x.z,x.w);
        o.z = pack2(y.x,y.y); o.w = pack2(y.z,y.w);
        return o;
    }
    return r.lo;
}
__device__ __forceinline__ uint4 load8(const void* p, size_t idx, int isf32){
    return cvt8(fetch8(p, idx, isf32), isf32);
}
__device__ __forceinline__ float loads(const void* p, size_t idx, int isf32){
    return isf32 ? ((const float*)p)[idx] : bf1(((const u16*)p)[idx]);
}
__device__ __forceinline__ float fast_tanh(float x){
    return 1.0f - 2.0f/(__expf(2.0f*x)+1.0f);
}
__device__ __forceinline__ float sigmoidf_(float x){
    return 1.0f/(1.0f+__expf(-x));
}

// ---------------- dtype detection ----------------
__global__ void k_detect(const u8* __restrict__ m, const u16* __restrict__ xj,
                         int* __restrict__ flags){
    __shared__ int n1, n2, n3, mb, xo;
    int t = threadIdx.x;
    if(t==0){ n1=0; n2=0; n3=0; mb=0; xo=0; }
    __syncthreads();
    int a1=0, a2=0, a3=0, amax=0;
    for(int i=t; i<8192; i+=256){
        int v = m[i]; int c = i&3;
        if(c==1) a1|=v;
        if(c==2) a2|=v;
        if(c==3) a3|=v;
        amax = amax > v ? amax : v;
    }
    if(a1) atomicOr(&n1,1);
    if(a2) atomicOr(&n2,1);
    if(a3) atomicOr(&n3,1);
    atomicMax(&mb, amax);
    int e = 0;
    for(int i=t; i<2048; i+=256){
        u32 u = xj[2*i];
        int ex = (u>>7)&0xFF;
        if(ex >= 156) e = 1;
    }
    if(e) atomicOr(&xo,1);
    __syncthreads();
    if(t==0){
        int w;
        if(!n1 && !n2 && !n3)      w = 4;   // int32
        else if(!n1 && n2 && n3)   w = 4;   // f32
        else if(mb > 1)            w = 2;   // bf16
        else                       w = 1;   // bool8
        flags[0] = w;
        flags[1] = xo;
    }
}

// ---------------- convert x_j and Ue to bf16 master copies (big-ws path) ----------------
__global__ __launch_bounds__(256) void k_conv(const void* __restrict__ xj,
                                              const void* __restrict__ Ue,
                                              const int* __restrict__ flags,
                                              u16* __restrict__ xj16,
                                              u16* __restrict__ ue16){
    int isf32 = flags[1];
    size_t g = (size_t)blockIdx.x*256 + threadIdx.x;
    if(g < 2097152){
        size_t idx = g*8;
        *(uint4*)&xj16[idx] = load8(xj, idx, isf32);
    } else {
        size_t idx = (g - 2097152)*8;
        *(uint4*)&ue16[idx] = load8(Ue, idx, isf32);
    }
}

// ---------------- hwe GEMM, K-split: grid (8 n, 8 kc, 2 m), 256 thr ----------------
__global__ __launch_bounds__(256) void k_hwe(const void* __restrict__ h,
                                             const void* __restrict__ We,
                                             const int* __restrict__ flags,
                                             float* __restrict__ hwe){
    int n0 = blockIdx.x*64;
    int kc = blockIdx.y*128;
    int m0 = blockIdx.z*128;
    int t = threadIdx.x;
    int isf32 = flags[1];
    __shared__ __align__(16) u16 As[128*40];
    __shared__ __align__(16) u16 Bs[64*40];
    int w = t>>6, lane = t&63;
    int q = lane>>4, l16 = lane&15;
    int koff = q*8;
    f4 acc[2][4];
    for(int mi=0;mi<2;mi++) for(int ni=0;ni<4;ni++){
        f4 z = {0.f,0.f,0.f,0.f}; acc[mi][ni] = z;
    }
    for(int ks=0; ks<128; ks+=32){
        __syncthreads();
        for(int i=0;i<2;i++){
            int row = i*64 + (t>>2), cv = t&3;
            uint4 va = load8(h, (size_t)(m0+row)*H_ + kc + ks + cv*8, isf32);
            *(uint4*)&As[row*40 + cv*8] = va;
        }
        {
            int row = t>>2, cv = t&3;
            uint4 vb = load8(We, (size_t)(n0+row)*H_ + kc + ks + cv*8, isf32);
            *(uint4*)&Bs[row*40 + cv*8] = vb;
        }
        __syncthreads();
        bf8 af[2], bfr[4];
        for(int mi=0;mi<2;mi++) af[mi]  = *(const bf8*)&As[(w*32+mi*16+l16)*40 + koff];
        for(int ni=0;ni<4;ni++) bfr[ni] = *(const bf8*)&Bs[(ni*16+l16)*40 + koff];
        for(int mi=0;mi<2;mi++)
            for(int ni=0;ni<4;ni++)
                acc[mi][ni] = __builtin_amdgcn_mfma_f32_16x16x32_bf16(af[mi], bfr[ni], acc[mi][ni], 0,0,0);
    }
    for(int mi=0;mi<2;mi++){
        for(int r=0;r<4;r++){
            int brow = m0 + w*32 + mi*16 + q*4 + r;
            for(int ni=0;ni<4;ni++){
                int ncol = n0 + ni*16 + l16;
                atomicAdd(&hwe[(size_t)brow*Hh_ + ncol], acc[mi][ni][r]);
            }
        }
    }
}

// ---------------- pack X_F | h | c into Xc[512:4096) as bf16 ----------------
__global__ __launch_bounds__(256) void k_pack(const void* __restrict__ XF,
                                              const void* __restrict__ h,
                                              const void* __restrict__ c,
                                              const int* __restrict__ flags,
                                              u16* __restrict__ Xc){
    int b = blockIdx.y;
    int r = blockIdx.x*256 + threadIdx.x;   // 0..3583
    int isf32 = flags[1];
    float v;
    if(r < DF_)            v = loads(XF, (size_t)b*DF_ + r, isf32);
    else if(r < DF_ + H_)  v = loads(h,  (size_t)b*H_ + (r - DF_), isf32);
    else                   v = loads(c,  (size_t)b*H_ + (r - DF_ - H_), isf32);
    Xc[(size_t)b*4096 + 512 + r] = f2bf(v);
}

// ---------------- attention e-score GEMM: grid (256 b, 8 n-tiles of 64), 256 thr ----------------
// Pipelined: register prefetch of next K-tile overlaps MFMA.
__global__ __launch_bounds__(256) void k_attn(const void* __restrict__ xjA,
                                              const void* __restrict__ wvec,
                                              const void* __restrict__ UeA,
                                              const void* __restrict__ be,
                                              const float* __restrict__ hwe,
                                              const int* __restrict__ flags,
                                              int srcbf,
                                              float* __restrict__ Epart){
    int b = blockIdx.x, nc = blockIdx.y, t = threadIdx.x;
    int isf = flags[1];               // for be/wvec (original inputs)
    int isA = srcbf ? 0 : isf;        // for xjA/UeA
    __shared__ __align__(16) u16 As[128*40];
    __shared__ __align__(16) u16 Bs[64*40];
    __shared__ float hwes[64];
    __shared__ float wvs[64];

    if(t < 64){
        int col = nc*64 + t;
        hwes[t] = hwe[(size_t)b*Hh_ + col] + loads(be, col, isf);
        wvs[t]  = loads(wvec, col, isf);
    }

    const size_t xboff = (size_t)b*O_*Hh_;
    int w = t>>6, lane = t&63;
    int q = lane>>4, l16 = lane&15;
    int koff = q*8;
    int rA = t>>2, cA = t&3;          // A rows rA, rA+64; B row rA (0..63)

    f4 acc[2][4];
    for(int mi=0;mi<2;mi++) for(int ni=0;ni<4;ni++){
        f4 z = {0.f,0.f,0.f,0.f}; acc[mi][ni] = z;
    }

    P8 pa0, pa1, pb;
    pa0 = fetch8(xjA, xboff + (size_t)rA*Hh_      + cA*8, isA);
    pa1 = fetch8(xjA, xboff + (size_t)(rA+64)*Hh_ + cA*8, isA);
    pb  = fetch8(UeA, (size_t)(nc*64 + rA)*Hh_    + cA*8, isA);

    for(int ks=0; ks<Hh_; ks+=32){
        __syncthreads();
        *(uint4*)&As[rA*40 + cA*8]      = cvt8(pa0, isA);
        *(uint4*)&As[(rA+64)*40 + cA*8] = cvt8(pa1, isA);
        *(uint4*)&Bs[rA*40 + cA*8]      = cvt8(pb, isA);
        __syncthreads();
        if(ks + 32 < Hh_){
            int kn = ks + 32;
            pa0 = fetch8(xjA, xboff + (size_t)rA*Hh_      + kn + cA*8, isA);
            pa1 = fetch8(xjA, xboff + (size_t)(rA+64)*Hh_ + kn + cA*8, isA);
            pb  = fetch8(UeA, (size_t)(nc*64 + rA)*Hh_    + kn + cA*8, isA);
        }
        bf8 af[2], bfr[4];
        for(int mi=0;mi<2;mi++) af[mi]  = *(const bf8*)&As[(w*32+mi*16+l16)*40 + koff];
        for(int ni=0;ni<4;ni++) bfr[ni] = *(const bf8*)&Bs[(ni*16+l16)*40 + koff];
        for(int mi=0;mi<2;mi++)
            for(int ni=0;ni<4;ni++)
                acc[mi][ni] = __builtin_amdgcn_mfma_f32_16x16x32_bf16(af[mi], bfr[ni], acc[mi][ni], 0,0,0);
    }
    // epilogue: each wave owns disjoint o-rows -> plain stores, no atomics
    for(int mi=0;mi<2;mi++){
        for(int r=0;r<4;r++){
            int o = w*32 + mi*16 + q*4 + r;
            float part = 0.f;
            for(int ni=0;ni<4;ni++){
                int col = ni*16 + l16;
                part += wvs[col] * fast_tanh(hwes[col] + acc[mi][ni][r]);
            }
            part += __shfl_xor(part, 1);
            part += __shfl_xor(part, 2);
            part += __shfl_xor(part, 4);
            part += __shfl_xor(part, 8);
            if(l16 == 0) Epart[(size_t)nc*32768 + (size_t)b*O_ + o] = part;
        }
    }
}

// ---------------- softmax + phi: grid 256 (per b), 512 thr ----------------
__global__ __launch_bounds__(512) void k_soft(const float* __restrict__ Epart,
                                              const void* __restrict__ maskp,
                                              const void* __restrict__ xjA,
                                              const int* __restrict__ flags,
                                              int srcbf,
                                              u16* __restrict__ Xc){
    int b = blockIdx.x, t = threadIdx.x;
    int isf = flags[1];
    int isA = srcbf ? 0 : isf;
    int mw = flags[0];
    __shared__ float es[O_];
    __shared__ float as_[O_];
    __shared__ float red[2];
    if(t < O_){
        float e = 0.f;
        for(int p=0;p<8;p++) e += Epart[(size_t)p*32768 + (size_t)b*O_ + t];
        size_t mi_ = (size_t)b*O_ + t;
        bool valid;
        if(mw == 1)      valid = ((const u8*)maskp)[mi_]  != 0;
        else if(mw == 2) valid = ((const u16*)maskp)[mi_] != 0;
        else             valid = ((const u32*)maskp)[mi_] != 0;
        es[t] = valid ? e : -1e30f;
    }
    __syncthreads();
    if(t < 64){
        float v = fmaxf(es[t], es[t+64]);
        for(int m=32;m>0;m>>=1) v = fmaxf(v, __shfl_xor(v, m));
        if(t==0) red[0] = v;
    }
    __syncthreads();
    if(t < O_) as_[t] = __expf(es[t] - red[0]);
    __syncthreads();
    if(t < 64){
        float v = as_[t] + as_[t+64];
        for(int m=32;m>0;m>>=1) v += __shfl_xor(v, m);
        if(t==0) red[1] = v;
    }
    __syncthreads();
    float inv = 1.0f / red[1];
    float acc = 0.f;
    size_t base = (size_t)b*O_*Hh_ + t;
    #pragma unroll 8
    for(int o=0;o<O_;o++){
        acc += as_[o] * loads(xjA, base + (size_t)o*Hh_, isA);
    }
    Xc[(size_t)b*4096 + t] = f2bf(acc * inv);
}

// ---------------- gates GEMM, K-split: grid (64 nt, 8 kc of 512), 512 thr, pipelined ----------------
__global__ __launch_bounds__(512) void k_gates(const u16* __restrict__ Xc,
    const void* __restrict__ Wi, const void* __restrict__ Wf, const void* __restrict__ Wc, const void* __restrict__ Wo,
    const void* __restrict__ Ui, const void* __restrict__ Uf, const void* __restrict__ Uc, const void* __restrict__ Uo,
    const void* __restrict__ Vi, const void* __restrict__ Vf, const void* __restrict__ Vo,
    const int* __restrict__ flags,
    float* __restrict__ pre){
    int nt = blockIdx.x;          // gate g = nt>>4, n-tile nt&15
    int kc = blockIdx.y;          // K-chunk of 512
    int g  = nt>>4;
    int k0 = kc*512;
    if(g == 2 && k0 >= 3072) return; // c-gate has no V peephole
    int isf32 = flags[1];
    const void* Wm = (g==0)?Wi:(g==1)?Wf:(g==2)?Wc:Wo;
    const void* Um = (g==0)?Ui:(g==1)?Uf:(g==2)?Uc:Uo;
    const void* Vm = (g==0)?Vi:(g==1)?Vf:(g==3)?Vo:Vi;  // g==2 never dereferences V
    int n0 = (nt&15)*64;
    int t = threadIdx.x;
    __shared__ __align__(16) u16 As[256*40];
    __shared__ __align__(16) u16 Bs[64*40];
    int w = t>>6, lane = t&63;
    int q = lane>>4, l16 = lane&15;
    int koff = q*8;
    int rA = t>>2, cA = t&3;      // A rows rA, rA+128 (rA 0..127); B row rA if t<256
    bool hasB = (t < 256);

    f4 acc[2][4];
    for(int mi=0;mi<2;mi++) for(int ni=0;ni<4;ni++){
        f4 z = {0.f,0.f,0.f,0.f}; acc[mi][ni] = z;
    }

    auto fetchB = [&](int k)->P8{
        int n = n0 + rA;
        if(k < 2048)       return fetch8(Wm, (size_t)n*I_ + k, isf32);
        else if(k < 3072)  return fetch8(Um, (size_t)n*H_ + (k-2048), isf32);
        else               return fetch8(Vm, (size_t)n*H_ + (k-3072), isf32);
    };

    uint4 qa0, qa1; P8 qb;
    qa0 = *(const uint4*)(Xc + (size_t)rA*4096       + k0 + cA*8);
    qa1 = *(const uint4*)(Xc + (size_t)(rA+128)*4096 + k0 + cA*8);
    if(hasB) qb = fetchB(k0 + cA*8);

    for(int ks=0; ks<512; ks+=32){
        __syncthreads();
        *(uint4*)&As[rA*40 + cA*8]       = qa0;
        *(uint4*)&As[(rA+128)*40 + cA*8] = qa1;
        if(hasB) *(uint4*)&Bs[rA*40 + cA*8] = cvt8(qb, isf32);
        __syncthreads();
        if(ks + 32 < 512){
            int kn = k0 + ks + 32;
            qa0 = *(const uint4*)(Xc + (size_t)rA*4096       + kn + cA*8);
            qa1 = *(const uint4*)(Xc + (size_t)(rA+128)*4096 + kn + cA*8);
            if(hasB) qb = fetchB(kn + cA*8);
        }
        bf8 af[2], bfr[4];
        for(int mi=0;mi<2;mi++) af[mi]  = *(const bf8*)&As[(w*32+mi*16+l16)*40 + koff];
        for(int ni=0;ni<4;ni++) bfr[ni] = *(const bf8*)&Bs[(ni*16+l16)*40 + koff];
        for(int mi=0;mi<2;mi++)
            for(int ni=0;ni<4;ni++)
                acc[mi][ni] = __builtin_amdgcn_mfma_f32_16x16x32_bf16(af[mi], bfr[ni], acc[mi][ni], 0,0,0);
    }
    float* pg = pre + (size_t)g*(B_*H_);
    for(int mi=0;mi<2;mi++){
        for(int r=0;r<4;r++){
            int brow = w*32 + mi*16 + q*4 + r;
            for(int ni=0;ni<4;ni++){
                int ncol = n0 + ni*16 + l16;
                atomicAdd(&pg[(size_t)brow*H_ + ncol], acc[mi][ni][r]);
            }
        }
    }
}

// ---------------- combine: f32 outputs ----------------
__global__ __launch_bounds__(256) void k_combine(const float* __restrict__ pre,
    const void* __restrict__ c,
    const void* __restrict__ bi, const void* __restrict__ bfv,
    const void* __restrict__ bc, const void* __restrict__ bo,
    const int* __restrict__ flags,
    float* __restrict__ out){
    int b = blockIdx.x, t = threadIdx.x;
    int isf32 = flags[1];
    const size_t G = (size_t)B_*H_;
    for(int i=0;i<4;i++){
        int n = i*256 + t;
        size_t idx = (size_t)b*H_ + n;
        float pi = pre[idx]       + loads(bi,  n, isf32);
        float pf = pre[G   + idx] + loads(bfv, n, isf32);
        float pc = pre[2*G + idx] + loads(bc,  n, isf32);
        float po = pre[3*G + idx] + loads(bo,  n, isf32);
        float ig = sigmoidf_(pi);
        float fg = sigmoidf_(pf);
        float og = sigmoidf_(po);
        float cold = loads(c, idx, isf32);
        float ncv = fg*cold + ig*fast_tanh(pc);
        float nh  = og*fast_tanh(ncv);
        out[idx]     = nh;    // new_h
        out[G + idx] = ncv;   // new_c
    }
}

extern "C" void kernel_launch(void* const* d_in, const int* in_sizes, int n_in,
                              void* d_out, int out_size, void* d_ws, size_t ws_size,
                              hipStream_t stream){
    const void* xj   = d_in[0];
    const void* mask = d_in[1];
    const void* XF   = d_in[2];
    const void* h    = d_in[3];
    const void* c    = d_in[4];
    const void* Wi   = d_in[5];
    const void* Wf   = d_in[6];
    const void* Wc   = d_in[7];
    const void* Wo   = d_in[8];
    const void* Ui   = d_in[9];
    const void* Uf   = d_in[10];
    const void* Uc   = d_in[11];
    const void* Uo   = d_in[12];
    const void* Vi   = d_in[13];
    const void* Vf   = d_in[14];
    // d_in[15] = V_c : unused by the reference
    const void* Vo   = d_in[16];
    const void* bi   = d_in[17];
    const void* bfv  = d_in[18];
    const void* bc   = d_in[19];
    const void* bo   = d_in[20];
    const void* wv   = d_in[21];
    const void* We   = d_in[22];
    const void* Ue   = d_in[23];
    const void* be   = d_in[24];

    char* ws = (char*)d_ws;
    float* hwe  = (float*)(ws + HWE_OFF);
    u16*   Xc   = (u16*)(ws + XC_OFF);
    float* pre  = (float*)(ws + PRE_OFF);   // also Epart during attention phase
    int*   flags= (int*)(ws + FLAG_OFF);
    float* out  = (float*)d_out;

    int big = (ws_size >= (size_t)WS_BIG);
    u16* xj16 = (u16*)(ws + XJ16_OFF);
    u16* ue16 = (u16*)(ws + UE16_OFF);
    const void* xjA = big ? (const void*)xj16 : xj;
    const void* UeA = big ? (const void*)ue16 : Ue;

    k_detect<<<1, 256, 0, stream>>>((const u8*)mask, (const u16*)xj, flags);
    hipMemsetAsync(hwe, 0, (size_t)B_*Hh_*sizeof(float), stream);
    if(big) k_conv<<<8320, 256, 0, stream>>>(xj, Ue, flags, xj16, ue16);
    k_hwe<<<dim3(8,8,2), 256, 0, stream>>>(h, We, flags, hwe);
    k_pack<<<dim3(14, B_), 256, 0, stream>>>(XF, h, c, flags, Xc);
    k_attn<<<dim3(B_, 8), 256, 0, stream>>>(xjA, wv, UeA, be, hwe, flags, big, pre);
    k_soft<<<B_, 512, 0, stream>>>(pre, mask, xjA, flags, big, Xc);
    hipMemsetAsync(pre, 0, (size_t)4*B_*H_*sizeof(float), stream);
    k_gates<<<dim3(64, 8), 512, 0, stream>>>(Xc, Wi,Wf,Wc,Wo, Ui,Uf,Uc,Uo, Vi,Vf,Vo, flags, pre);
    k_combine<<<B_, 256, 0, stream>>>(pre, c, bi, bfv, bc, bo, flags, out);
}